// Round 23
// baseline (70599.780 us; speedup 1.0000x reference)
//
#include <hip/hip_runtime.h>
#include <float.h>
#include <math.h>

typedef unsigned int u32;

// ---------------------------------------------------------------- helpers
__device__ __forceinline__ u32 fkey32(float f) {
    u32 b = __float_as_uint(f);
    return (b & 0x80000000u) ? ~b : (b | 0x80000000u);
}
__device__ __forceinline__ float funkey32(u32 k) {
    u32 b = (k & 0x80000000u) ? (k & 0x7fffffffu) : ~k;
    return __uint_as_float(b);
}

// ---------------------------------------------------------------- sentinel
__global__ void d_sent(float* out, int n, float v) {
    int i = blockIdx.x * 256 + threadIdx.x;
    if (i < n) out[i] = v;
}

// ------------------------- xs (f32, non-FMA sequential K=3) + key init
__global__ void f_xs(const float* __restrict__ x, const float* __restrict__ pos,
                     const float* __restrict__ w, const float* __restrict__ b,
                     float* __restrict__ xs, u32* __restrict__ key, int N) {
    int i = blockIdx.x * 256 + threadIdx.x;
    if (i >= N * 64) return;
    int n = i >> 6, h = i & 63;
    float t = __fmul_rn(x[n], w[h]);
    t = __fadd_rn(t, __fmul_rn(pos[2 * n], w[64 + h]));
    t = __fadd_rn(t, __fmul_rn(pos[2 * n + 1], w[128 + h]));
    t = __fadd_rn(t, b[h]);
    xs[i] = fmaxf(t, 0.f);
    key[i] = fkey32(-INFINITY);
}

__global__ void d_deg(const int* __restrict__ src, int* __restrict__ deg, int E) {
    int e = blockIdx.x * 256 + threadIdx.x;
    if (e < E) atomicAdd(&deg[src[e]], 1);
}

// ------------------------- EdgeConv f32 (non-FMA sequential K=128)
__global__ __launch_bounds__(256) void f_edgeconv(
    const float* __restrict__ xs, const int* __restrict__ src, const int* __restrict__ dst,
    const float* __restrict__ w1, const float* __restrict__ b1,
    const float* __restrict__ w2, const float* __restrict__ b2,
    u32* __restrict__ key, int E) {
    int e = blockIdx.x * 256 + threadIdx.x;
    if (e >= E) return;
    int s = src[e], d = dst[e];
    const float* xi = xs + (size_t)d * 64;
    const float* xj = xs + (size_t)s * 64;
    float df[64];
    for (int c = 0; c < 64; ++c) df[c] = __fsub_rn(xj[c], xi[c]);
    float hid[64];
    for (int o = 0; o < 64; ++o) {
        float acc = __fmul_rn(xi[0], w1[o]);
        for (int c = 1; c < 64; ++c)
            acc = __fadd_rn(acc, __fmul_rn(xi[c], w1[c * 64 + o]));
        for (int c = 0; c < 64; ++c)
            acc = __fadd_rn(acc, __fmul_rn(df[c], w1[(64 + c) * 64 + o]));
        acc = __fadd_rn(acc, b1[o]);
        hid[o] = fmaxf(acc, 0.f);
    }
    u32* kp = key + (size_t)d * 64;
    for (int h = 0; h < 64; ++h) {
        float m = __fmul_rn(hid[0], w2[h]);
        for (int o = 1; o < 64; ++o)
            m = __fadd_rn(m, __fmul_rn(hid[o], w2[o * 64 + h]));
        m = __fadd_rn(m, b2[h]);
        atomicMax(&kp[h], fkey32(m));
    }
}

// keys -> xs2 f32 in place (isolated -> -inf -> 0)
__global__ void f_xs2(u32* __restrict__ agg, int total) {
    int i = blockIdx.x * 256 + threadIdx.x;
    if (i >= total) return;
    float v = funkey32(agg[i]);
    reinterpret_cast<float*>(agg)[i] = fmaxf(v, 0.f);
}

// transpose f32 for coalesced assignment dots
__global__ void f_transpose(const float* __restrict__ X, float* __restrict__ XT, int N) {
    int t = blockIdx.x * 256 + threadIdx.x;
    if (t >= N * 64) return;
    int d = t / N, i = t - d * N;
    XT[t] = X[(size_t)i * 64 + d];
}

// xx[i] = (X[i]*X[i]).sum() -- numpy pairwise-8 strided accumulators, forced rn
__global__ void f_xx(const float* __restrict__ X, float* __restrict__ xx, int N) {
    int i = blockIdx.x * 256 + threadIdx.x;
    if (i >= N) return;
    const float* row = X + (size_t)i * 64;
    float r[8] = {0, 0, 0, 0, 0, 0, 0, 0};
    for (int d = 0; d < 64; ++d)
        r[d & 7] = __fadd_rn(r[d & 7], __fmul_rn(row[d], row[d]));
    float a01 = __fadd_rn(r[0], r[1]), a23 = __fadd_rn(r[2], r[3]);
    float a45 = __fadd_rn(r[4], r[5]), a67 = __fadd_rn(r[6], r[7]);
    xx[i] = __fadd_rn(__fadd_rn(a01, a23), __fadd_rn(a45, a67));
}

// numpy pairwise_sum over 128 contiguous floats (8-accumulator pattern)
__device__ float np_pairwise128(const float* a) {
    float r0 = a[0], r1 = a[1], r2 = a[2], r3 = a[3];
    float r4 = a[4], r5 = a[5], r6 = a[6], r7 = a[7];
    for (int i = 8; i < 128; i += 8) {
        r0 = __fadd_rn(r0, a[i + 0]); r1 = __fadd_rn(r1, a[i + 1]);
        r2 = __fadd_rn(r2, a[i + 2]); r3 = __fadd_rn(r3, a[i + 3]);
        r4 = __fadd_rn(r4, a[i + 4]); r5 = __fadd_rn(r5, a[i + 5]);
        r6 = __fadd_rn(r6, a[i + 6]); r7 = __fadd_rn(r7, a[i + 7]);
    }
    float a01 = __fadd_rn(r0, r1), a23 = __fadd_rn(r2, r3);
    float a45 = __fadd_rn(r4, r5), a67 = __fadd_rn(r6, r7);
    return __fadd_rn(__fadd_rn(a01, a23), __fadd_rn(a45, a67));
}

// ------------------ kmeans f32, np semantics (partition proven invariant)
__global__ __launch_bounds__(256) void f_kmeans(
    const float* __restrict__ X, const float* __restrict__ XT,
    const float* __restrict__ xx, const int* __restrict__ init_idx,
    unsigned char* __restrict__ asg8, int* __restrict__ assign, int N) {
    __shared__ float cent[256];
    __shared__ float cc[4];
    __shared__ float snew[256];
    __shared__ float ssq[256];
    __shared__ float sdiff;
    const int t = threadIdx.x;

    cent[t] = X[(size_t)init_idx[t >> 6] * 64 + (t & 63)];
    __syncthreads();

    for (int it = 0; it < 300; ++it) {
        if (t < 4) {
            float r[8] = {0, 0, 0, 0, 0, 0, 0, 0};
            for (int d = 0; d < 64; ++d) {
                float v = cent[t * 64 + d];
                r[d & 7] = __fadd_rn(r[d & 7], __fmul_rn(v, v));
            }
            float a01 = __fadd_rn(r[0], r[1]), a23 = __fadd_rn(r[2], r[3]);
            float a45 = __fadd_rn(r[4], r[5]), a67 = __fadd_rn(r[6], r[7]);
            cc[t] = __fadd_rn(__fadd_rn(a01, a23), __fadd_rn(a45, a67));
        }
        __syncthreads();
        for (int i = t; i < N; i += 256) {
            float d0 = __fmul_rn(XT[i], cent[0]);
            float d1 = __fmul_rn(XT[i], cent[64]);
            float d2 = __fmul_rn(XT[i], cent[128]);
            float d3 = __fmul_rn(XT[i], cent[192]);
            for (int d = 1; d < 64; ++d) {
                float xv = XT[(size_t)d * N + i];
                d0 = __fadd_rn(d0, __fmul_rn(xv, cent[d]));
                d1 = __fadd_rn(d1, __fmul_rn(xv, cent[64 + d]));
                d2 = __fadd_rn(d2, __fmul_rn(xv, cent[128 + d]));
                d3 = __fadd_rn(d3, __fmul_rn(xv, cent[192 + d]));
            }
            float xi = xx[i];
            float q0 = __fsub_rn(__fadd_rn(xi, cc[0]), __fmul_rn(2.0f, d0));
            float q1 = __fsub_rn(__fadd_rn(xi, cc[1]), __fmul_rn(2.0f, d1));
            float q2 = __fsub_rn(__fadd_rn(xi, cc[2]), __fmul_rn(2.0f, d2));
            float q3 = __fsub_rn(__fadd_rn(xi, cc[3]), __fmul_rn(2.0f, d3));
            int kb = 0; float bv = q0;
            if (q1 < bv) { bv = q1; kb = 1; }
            if (q2 < bv) { bv = q2; kb = 2; }
            if (q3 < bv) { bv = q3; kb = 3; }
            asg8[i] = (unsigned char)kb;
        }
        __syncthreads();
        {
            int k = t >> 6, f = t & 63;
            float s = 0.f, c = 0.f;
            for (int i = 0; i < N; ++i) {
                if ((int)asg8[i] == k) {
                    s = __fadd_rn(s, X[(size_t)i * 64 + f]);
                    c = __fadd_rn(c, 1.0f);
                }
            }
            float cold = cent[t];
            float ncv = (c > 0.f) ? __fdiv_rn(s, fmaxf(c, 1.f)) : cold;
            float dd = __fsub_rn(ncv, cold);
            snew[t] = ncv;
            ssq[t] = __fmul_rn(dd, dd);
        }
        __syncthreads();
        if (t == 0) {
            float left  = np_pairwise128(ssq);
            float right = np_pairwise128(ssq + 128);
            sdiff = sqrtf(__fadd_rn(left, right));
        }
        __syncthreads();
        cent[t] = snew[t];
        __syncthreads();
        if (sdiff < 1e-4f) break;
    }
    if (t < 4) {
        float r[8] = {0, 0, 0, 0, 0, 0, 0, 0};
        for (int d = 0; d < 64; ++d) {
            float v = cent[t * 64 + d];
            r[d & 7] = __fadd_rn(r[d & 7], __fmul_rn(v, v));
        }
        float a01 = __fadd_rn(r[0], r[1]), a23 = __fadd_rn(r[2], r[3]);
        float a45 = __fadd_rn(r[4], r[5]), a67 = __fadd_rn(r[6], r[7]);
        cc[t] = __fadd_rn(__fadd_rn(a01, a23), __fadd_rn(a45, a67));
    }
    __syncthreads();
    for (int i = t; i < N; i += 256) {
        float d0 = __fmul_rn(XT[i], cent[0]);
        float d1 = __fmul_rn(XT[i], cent[64]);
        float d2 = __fmul_rn(XT[i], cent[128]);
        float d3 = __fmul_rn(XT[i], cent[192]);
        for (int d = 1; d < 64; ++d) {
            float xv = XT[(size_t)d * N + i];
            d0 = __fadd_rn(d0, __fmul_rn(xv, cent[d]));
            d1 = __fadd_rn(d1, __fmul_rn(xv, cent[64 + d]));
            d2 = __fadd_rn(d2, __fmul_rn(xv, cent[128 + d]));
            d3 = __fadd_rn(d3, __fmul_rn(xv, cent[192 + d]));
        }
        float xi = xx[i];
        float q0 = __fsub_rn(__fadd_rn(xi, cc[0]), __fmul_rn(2.0f, d0));
        float q1 = __fsub_rn(__fadd_rn(xi, cc[1]), __fmul_rn(2.0f, d1));
        float q2 = __fsub_rn(__fadd_rn(xi, cc[2]), __fmul_rn(2.0f, d2));
        float q3 = __fsub_rn(__fadd_rn(xi, cc[3]), __fmul_rn(2.0f, d3));
        int kb = 0; float bv = q0;
        if (q1 < bv) { bv = q1; kb = 1; }
        if (q2 < bv) { bv = q2; kb = 2; }
        if (q3 < bv) { bv = q3; kb = 3; }
        assign[i] = kb;
    }
}

// ----------------------------------------------- conv4 f64 (continuous, safe)
__global__ __launch_bounds__(256) void d_conv4(
    const float* __restrict__ edge_attr, const int* __restrict__ src,
    const int* __restrict__ dst, const int* __restrict__ assign,
    const int* __restrict__ deg, const float* __restrict__ w,
    const float* __restrict__ alpha, double* __restrict__ eacc, int E) {
    int e = blockIdx.x * 256 + threadIdx.x;
    if (e >= E) return;
    int s = src[e], d = dst[e];
    int ka = assign[s];
    if (assign[d] != ka) return;
    double a = (double)edge_attr[e];
    double f0[64], f1[64], f2[64], f3[64];
    for (int j = 0; j < 64; ++j) {
        double h0 = a * (double)w[j];
        double h1 = a * (double)w[64 + j];
        double h2 = a * (double)w[128 + j];
        double h3 = a * (double)w[192 + j];
        double l1 = h1 > 0.0 ? h1 : 0.1 * h1;
        double l2 = h2 > 0.0 ? h2 : 0.1 * h2;
        double l3 = h3 > 0.0 ? h3 : 0.1 * h3;
        f0[j] = h0;
        f1[j] = l1;
        f2[j] = l2 * l2;
        f3[j] = (l3 * l3) * l3;
    }
    double dg = (double)deg[s];
    const float* ab = alpha + (size_t)ka * 4 * 64 * 64;
    double* ep = eacc + (size_t)d * 64;
    for (int h = 0; h < 64; ++h) {
        const float* a0 = ab + (size_t)(0 * 64 + h) * 64;
        const float* a1 = ab + (size_t)(1 * 64 + h) * 64;
        const float* a2 = ab + (size_t)(2 * 64 + h) * 64;
        const float* a3 = ab + (size_t)(3 * 64 + h) * 64;
        double s0 = 0.0, s1 = 0.0, s2 = 0.0, s3 = 0.0;
        for (int j = 0; j < 64; ++j) {
            s0 = fma(f0[j], (double)a0[j], s0);
            s1 = fma(f1[j], (double)a1[j], s1);
            s2 = fma(f2[j], (double)a2[j], s2);
            s3 = fma(f3[j], (double)a3[j], s3);
        }
        double ew = ((s0 + s1) + s2) + s3;
        atomicAdd(&ep[h], ew / dg);
    }
}

// z[n] = sum_h eacc[n,h]*w3[h] + x[n]*w3[64]
__global__ void d_z(const double* __restrict__ eacc, const float* __restrict__ x,
                    const float* __restrict__ w3, double* __restrict__ z, int N) {
    int n = blockIdx.x * 256 + threadIdx.x;
    if (n >= N) return;
    const double* row = eacc + (size_t)n * 64;
    double v = 0.0;
    for (int h = 0; h < 64; ++h)
        v = fma(row[h], (double)w3[h], v);
    z[n] = v + (double)x[n] * (double)w3[64];
}

// qq[j] = (px*px)+(py*py), separate roundings
__global__ void f_pp(const float* __restrict__ pl, float* __restrict__ pp, int N) {
    int i = blockIdx.x * 256 + threadIdx.x;
    if (i < N) {
        float px = pl[2 * i], py = pl[2 * i + 1];
        pp[i] = __fadd_rn(__fmul_rn(px, px), __fmul_rn(py, py));
    }
}

// -- KNN(4) f32 V6: nonFMA dot + FMA-contracted combine, FIRST-index ties
__global__ __launch_bounds__(256) void f_knn_out(
    const float* __restrict__ ph, const float* __restrict__ pl,
    const float* __restrict__ pp, const double* __restrict__ z,
    const float* __restrict__ c3b, float* __restrict__ out, int N, int NH) {
    int p = blockIdx.x * 256 + threadIdx.x;
    if (p >= NH) return;
    float hx = ph[2 * p], hy = ph[2 * p + 1];
    float hh = __fadd_rn(__fmul_rn(hx, hx), __fmul_rn(hy, hy));
    float b0 = FLT_MAX, b1 = FLT_MAX, b2 = FLT_MAX, b3 = FLT_MAX;
    int j0 = 0, j1 = 0, j2 = 0, j3 = 0;
    for (int j = 0; j < N; ++j) {
        // V6: dot unfused, combine contracted to fma(-2, dot, t1)
        float dot = __fadd_rn(__fmul_rn(hx, pl[2 * j]), __fmul_rn(hy, pl[2 * j + 1]));
        float t1  = __fadd_rn(hh, pp[j]);
        float dv  = __fmaf_rn(-2.0f, dot, t1);
        if (dv < b3) {
            if (dv < b2) {
                b3 = b2; j3 = j2;
                if (dv < b1) {
                    b2 = b1; j2 = j1;
                    if (dv < b0) { b1 = b0; j1 = j0; b0 = dv; j0 = j; }
                    else         { b1 = dv; j1 = j; }
                } else { b2 = dv; j2 = j; }
            } else { b3 = dv; j3 = j; }
        }
    }
    double zz = ((z[j0] + z[j1]) + z[j2]) + z[j3];
    out[p] = (float)(0.25 * zz + (double)c3b[0]);
}

// ------------------------------------------------------------------- launch
extern "C" void kernel_launch(void* const* d_in, const int* in_sizes, int n_in,
                              void* d_out, int out_size, void* d_ws, size_t ws_size,
                              hipStream_t stream) {
    float* out = (float*)d_out;

    static const int EXP[18] = {10000, 160000, 20000, 40000, 192, 64, 8192, 64,
                                4096, 64, 256, 65536, 256, 65536, 65, 1, 320000, 4};
    int bad = -1;
    if (n_in != 18) bad = 19;
    else for (int i = 0; i < 18; ++i) if (in_sizes[i] != EXP[i]) { bad = i; break; }
    if (bad >= 0) {
        d_sent<<<(out_size + 255) / 256, 256, 0, stream>>>(out, out_size,
                                                           ldexpf(1.0f, 30 + bad));
        return;
    }

    const float* x         = (const float*)d_in[0];
    const float* edge_attr = (const float*)d_in[1];
    const float* pos       = (const float*)d_in[2];
    const float* pos_high  = (const float*)d_in[3];
    const float* lin_w     = (const float*)d_in[4];
    const float* lin_b     = (const float*)d_in[5];
    const float* ec_w1     = (const float*)d_in[6];
    const float* ec_b1     = (const float*)d_in[7];
    const float* ec_w2     = (const float*)d_in[8];
    const float* ec_b2     = (const float*)d_in[9];
    const float* c4w       = (const float*)d_in[12];
    const float* c4a       = (const float*)d_in[13];
    const float* c3w       = (const float*)d_in[14];
    const float* c3b       = (const float*)d_in[15];
    const int*   eidx      = (const int*)d_in[16];
    const int*   kinit     = (const int*)d_in[17];
    int N  = in_sizes[0];
    int E  = in_sizes[1];
    int NH = in_sizes[3] / 2;
    const int* src  = eidx;
    const int* dstA = eidx + E;

    char* wsb = (char*)d_ws;
    size_t off = 0;
    auto alloc = [&](size_t bytes) -> char* {
        char* pp = wsb + off;
        off += (bytes + 255) & ~(size_t)255;
        return pp;
    };
    float*  XS   = (float*)alloc((size_t)N * 64 * 4);
    u32*    KEY  = (u32*)alloc((size_t)N * 64 * 4);     // -> xs2 f32 in place
    float*  XT   = (float*)alloc((size_t)N * 64 * 4);
    float*  XX   = (float*)alloc((size_t)N * 4);
    double* EACC = (double*)alloc((size_t)N * 64 * 8);
    int*    DEG  = (int*)alloc((size_t)N * 4);
    int*    ASG  = (int*)alloc((size_t)N * 4);
    unsigned char* ASG8 = (unsigned char*)alloc((size_t)N);
    double* Z    = (double*)alloc((size_t)N * 8);
    float*  PP   = (float*)alloc((size_t)N * 4);

    if (off > ws_size) {
        d_sent<<<(out_size + 255) / 256, 256, 0, stream>>>(out, out_size,
                                                           ldexpf(1.0f, 29));
        return;
    }

    hipMemsetAsync(DEG, 0, (size_t)N * 4, stream);
    hipMemsetAsync(EACC, 0, (size_t)N * 64 * 8, stream);

    f_xs<<<(N * 64 + 255) / 256, 256, 0, stream>>>(x, pos, lin_w, lin_b, XS, KEY, N);
    d_deg<<<(E + 255) / 256, 256, 0, stream>>>(src, DEG, E);
    f_edgeconv<<<(E + 255) / 256, 256, 0, stream>>>(XS, src, dstA, ec_w1, ec_b1,
                                                    ec_w2, ec_b2, KEY, E);
    f_xs2<<<(N * 64 + 255) / 256, 256, 0, stream>>>(KEY, N * 64);
    float* X2 = (float*)KEY;
    f_transpose<<<(N * 64 + 255) / 256, 256, 0, stream>>>(X2, XT, N);
    f_xx<<<(N + 255) / 256, 256, 0, stream>>>(X2, XX, N);
    f_kmeans<<<1, 256, 0, stream>>>(X2, XT, XX, kinit, ASG8, ASG, N);
    d_conv4<<<(E + 255) / 256, 256, 0, stream>>>(edge_attr, src, dstA, ASG, DEG,
                                                 c4w, c4a, EACC, E);
    d_z<<<(N + 255) / 256, 256, 0, stream>>>(EACC, x, c3w, Z, N);
    f_pp<<<(N + 255) / 256, 256, 0, stream>>>(pos, PP, N);
    f_knn_out<<<(NH + 255) / 256, 256, 0, stream>>>(pos_high, pos, PP, Z, c3b,
                                                    out, N, NH);
}

// Round 24
// 4345.227 us; speedup vs baseline: 16.2477x; 16.2477x over previous
//
#include <hip/hip_runtime.h>
#include <hip/hip_cooperative_groups.h>
#include <float.h>
#include <math.h>

namespace cg = cooperative_groups;
typedef unsigned int u32;

// ---------------------------------------------------------------- helpers
__device__ __forceinline__ u32 fkey32(float f) {
    u32 b = __float_as_uint(f);
    return (b & 0x80000000u) ? ~b : (b | 0x80000000u);
}
__device__ __forceinline__ float funkey32(u32 k) {
    u32 b = (k & 0x80000000u) ? (k & 0x7fffffffu) : ~k;
    return __uint_as_float(b);
}

// ---------------------------------------------------------------- sentinel
__global__ void d_sent(float* out, int n, float v) {
    int i = blockIdx.x * 256 + threadIdx.x;
    if (i < n) out[i] = v;
}

// ------------------------- xs (f32, non-FMA sequential K=3) + key init
__global__ void f_xs(const float* __restrict__ x, const float* __restrict__ pos,
                     const float* __restrict__ w, const float* __restrict__ b,
                     float* __restrict__ xs, u32* __restrict__ key, int N) {
    int i = blockIdx.x * 256 + threadIdx.x;
    if (i >= N * 64) return;
    int n = i >> 6, h = i & 63;
    float t = __fmul_rn(x[n], w[h]);
    t = __fadd_rn(t, __fmul_rn(pos[2 * n], w[64 + h]));
    t = __fadd_rn(t, __fmul_rn(pos[2 * n + 1], w[128 + h]));
    t = __fadd_rn(t, b[h]);
    xs[i] = fmaxf(t, 0.f);
    key[i] = fkey32(-INFINITY);
}

__global__ void d_deg(const int* __restrict__ src, int* __restrict__ deg, int E) {
    int e = blockIdx.x * 256 + threadIdx.x;
    if (e < E) atomicAdd(&deg[src[e]], 1);
}

// ------------------------- EdgeConv f32 (non-FMA sequential, R23-exact)
__global__ __launch_bounds__(256) void f_edgeconv(
    const float* __restrict__ xs, const int* __restrict__ src, const int* __restrict__ dst,
    const float* __restrict__ w1, const float* __restrict__ b1,
    const float* __restrict__ w2, const float* __restrict__ b2,
    u32* __restrict__ key, int E) {
    int e = blockIdx.x * 256 + threadIdx.x;
    if (e >= E) return;
    int s = src[e], d = dst[e];
    const float* xi = xs + (size_t)d * 64;
    const float* xj = xs + (size_t)s * 64;
    float df[64];
    for (int c = 0; c < 64; ++c) df[c] = __fsub_rn(xj[c], xi[c]);
    float hid[64];
    for (int o = 0; o < 64; ++o) {
        float acc = __fmul_rn(xi[0], w1[o]);
        for (int c = 1; c < 64; ++c)
            acc = __fadd_rn(acc, __fmul_rn(xi[c], w1[c * 64 + o]));
        for (int c = 0; c < 64; ++c)
            acc = __fadd_rn(acc, __fmul_rn(df[c], w1[(64 + c) * 64 + o]));
        acc = __fadd_rn(acc, b1[o]);
        hid[o] = fmaxf(acc, 0.f);
    }
    u32* kp = key + (size_t)d * 64;
    for (int h = 0; h < 64; ++h) {
        float m = __fmul_rn(hid[0], w2[h]);
        for (int o = 1; o < 64; ++o)
            m = __fadd_rn(m, __fmul_rn(hid[o], w2[o * 64 + h]));
        m = __fadd_rn(m, b2[h]);
        atomicMax(&kp[h], fkey32(m));
    }
}

// keys -> xs2 f32 in place
__global__ void f_xs2(u32* __restrict__ agg, int total) {
    int i = blockIdx.x * 256 + threadIdx.x;
    if (i >= total) return;
    float v = funkey32(agg[i]);
    reinterpret_cast<float*>(agg)[i] = fmaxf(v, 0.f);
}

__global__ void f_transpose(const float* __restrict__ X, float* __restrict__ XT, int N) {
    int t = blockIdx.x * 256 + threadIdx.x;
    if (t >= N * 64) return;
    int d = t / N, i = t - d * N;
    XT[t] = X[(size_t)i * 64 + d];
}

// xx[i] -- numpy pairwise-8, forced rn (R23-exact)
__global__ void f_xx(const float* __restrict__ X, float* __restrict__ xx, int N) {
    int i = blockIdx.x * 256 + threadIdx.x;
    if (i >= N) return;
    const float* row = X + (size_t)i * 64;
    float r[8] = {0, 0, 0, 0, 0, 0, 0, 0};
    for (int d = 0; d < 64; ++d)
        r[d & 7] = __fadd_rn(r[d & 7], __fmul_rn(row[d], row[d]));
    float a01 = __fadd_rn(r[0], r[1]), a23 = __fadd_rn(r[2], r[3]);
    float a45 = __fadd_rn(r[4], r[5]), a67 = __fadd_rn(r[6], r[7]);
    xx[i] = __fadd_rn(__fadd_rn(a01, a23), __fadd_rn(a45, a67));
}

__device__ float np_pairwise128(const float* a) {
    float r0 = a[0], r1 = a[1], r2 = a[2], r3 = a[3];
    float r4 = a[4], r5 = a[5], r6 = a[6], r7 = a[7];
    for (int i = 8; i < 128; i += 8) {
        r0 = __fadd_rn(r0, a[i + 0]); r1 = __fadd_rn(r1, a[i + 1]);
        r2 = __fadd_rn(r2, a[i + 2]); r3 = __fadd_rn(r3, a[i + 3]);
        r4 = __fadd_rn(r4, a[i + 4]); r5 = __fadd_rn(r5, a[i + 5]);
        r6 = __fadd_rn(r6, a[i + 6]); r7 = __fadd_rn(r7, a[i + 7]);
    }
    float a01 = __fadd_rn(r0, r1), a23 = __fadd_rn(r2, r3);
    float a45 = __fadd_rn(r4, r5), a67 = __fadd_rn(r6, r7);
    return __fadd_rn(__fadd_rn(a01, a23), __fadd_rn(a45, a67));
}

// ---------------- kmeans COOPERATIVE: 64 blocks x 1024 (partition-equivalent)
// Per-point assignment expression is bit-identical to R23; accumulation uses
// the proven-invariant chunked fixed-order family (R2/R6 pattern).
#define KG 64
#define KB 1024
__global__ __launch_bounds__(KB) void f_kmeans_coop(
    const float* __restrict__ X, const float* __restrict__ XT,
    const float* __restrict__ xx, const int* __restrict__ init_idx,
    float* __restrict__ part, float* __restrict__ cnts,
    unsigned char* __restrict__ asg8, int* __restrict__ assign, int N) {
    cg::grid_group grid = cg::this_grid();
    __shared__ float cent[256];
    __shared__ float cc[4];
    __shared__ float sacc[4][256];   // quarter partials
    __shared__ float scnt[4][4];
    __shared__ float ssq[256];
    __shared__ float snew[256];
    __shared__ float sdiff;
    const int t = threadIdx.x;
    const int b = blockIdx.x;

    if (t < 256) cent[t] = X[(size_t)init_idx[t >> 6] * 64 + (t & 63)];
    __syncthreads();

    const int chunk = (N + KG - 1) / KG;
    const int lo = b * chunk;
    const int clen = max(0, min(chunk, N - lo));

    for (int it = 0; it < 300; ++it) {
        if (t < 4) {   // (c*c).sum -- pairwise-8, forced rn (bit-identical)
            float r[8] = {0, 0, 0, 0, 0, 0, 0, 0};
            for (int d = 0; d < 64; ++d) {
                float v = cent[t * 64 + d];
                r[d & 7] = __fadd_rn(r[d & 7], __fmul_rn(v, v));
            }
            float a01 = __fadd_rn(r[0], r[1]), a23 = __fadd_rn(r[2], r[3]);
            float a45 = __fadd_rn(r[4], r[5]), a67 = __fadd_rn(r[6], r[7]);
            cc[t] = __fadd_rn(__fadd_rn(a01, a23), __fadd_rn(a45, a67));
        }
        __syncthreads();
        // phase A: assignment of THIS block's chunk (bit-identical expression)
        for (int i = lo + t; i < lo + clen; i += KB) {
            float d0 = __fmul_rn(XT[i], cent[0]);
            float d1 = __fmul_rn(XT[i], cent[64]);
            float d2 = __fmul_rn(XT[i], cent[128]);
            float d3 = __fmul_rn(XT[i], cent[192]);
            for (int d = 1; d < 64; ++d) {
                float xv = XT[(size_t)d * N + i];
                d0 = __fadd_rn(d0, __fmul_rn(xv, cent[d]));
                d1 = __fadd_rn(d1, __fmul_rn(xv, cent[64 + d]));
                d2 = __fadd_rn(d2, __fmul_rn(xv, cent[128 + d]));
                d3 = __fadd_rn(d3, __fmul_rn(xv, cent[192 + d]));
            }
            float xi = xx[i];
            float q0 = __fsub_rn(__fadd_rn(xi, cc[0]), __fmul_rn(2.0f, d0));
            float q1 = __fsub_rn(__fadd_rn(xi, cc[1]), __fmul_rn(2.0f, d1));
            float q2 = __fsub_rn(__fadd_rn(xi, cc[2]), __fmul_rn(2.0f, d2));
            float q3 = __fsub_rn(__fadd_rn(xi, cc[3]), __fmul_rn(2.0f, d3));
            int kb = 0; float bv = q0;
            if (q1 < bv) { bv = q1; kb = 1; }
            if (q2 < bv) { bv = q2; kb = 2; }
            if (q3 < bv) { bv = q3; kb = 3; }
            asg8[i] = (unsigned char)kb;
        }
        __syncthreads();
        // phase B: thread (q,k,f); quarter q scans its sub-chunk sequentially
        {
            int q = t >> 8, kf = t & 255, k = kf >> 6, f = kf & 63;
            int Nq = (clen + 3) >> 2;
            int qlo = lo + q * Nq, qhi = qlo + Nq;
            if (qhi > lo + clen) qhi = lo + clen;
            float s = 0.f, c = 0.f;
            for (int i = qlo; i < qhi; ++i) {
                if ((int)asg8[i] == k) {
                    s = __fadd_rn(s, X[(size_t)i * 64 + f]);
                    c = __fadd_rn(c, 1.0f);
                }
            }
            sacc[q][kf] = s;
            if (f == 0) scnt[q][k] = c;
        }
        __syncthreads();
        // combine quarters in fixed order -> block partials to global
        float* pb = part + (it & 1) * (KG * 256);
        float* cb = cnts + (it & 1) * (KG * 4);
        if (t < 256) {
            int k = t >> 6;
            float s = __fadd_rn(__fadd_rn(__fadd_rn(sacc[0][t], sacc[1][t]),
                                          sacc[2][t]), sacc[3][t]);
            pb[b * 256 + t] = s;
            if ((t & 63) == 0) {
                float c = __fadd_rn(__fadd_rn(__fadd_rn(scnt[0][k], scnt[1][k]),
                                              scnt[2][k]), scnt[3][k]);
                cb[b * 4 + k] = c;
            }
        }
        __threadfence();
        grid.sync();
        // phase C: every block redundantly reduces in fixed block order
        if (t < 256) {
            int k = t >> 6;
            float s = 0.f;
            for (int bb = 0; bb < KG; ++bb) s = __fadd_rn(s, pb[bb * 256 + t]);
            float c = 0.f;
            for (int bb = 0; bb < KG; ++bb) c = __fadd_rn(c, cb[bb * 4 + k]);
            float cold = cent[t];
            float ncv = (c > 0.f) ? __fdiv_rn(s, fmaxf(c, 1.f)) : cold;
            float dd = __fsub_rn(ncv, cold);
            snew[t] = ncv;
            ssq[t] = __fmul_rn(dd, dd);
        }
        __syncthreads();
        if (t == 0) {
            float left  = np_pairwise128(ssq);
            float right = np_pairwise128(ssq + 128);
            sdiff = sqrtf(__fadd_rn(left, right));
        }
        __syncthreads();
        if (t < 256) cent[t] = snew[t];
        __syncthreads();
        if (sdiff < 1e-4f) break;   // identical decision in every block
    }
    // final assignment of this block's chunk (bit-identical expression)
    if (t < 4) {
        float r[8] = {0, 0, 0, 0, 0, 0, 0, 0};
        for (int d = 0; d < 64; ++d) {
            float v = cent[t * 64 + d];
            r[d & 7] = __fadd_rn(r[d & 7], __fmul_rn(v, v));
        }
        float a01 = __fadd_rn(r[0], r[1]), a23 = __fadd_rn(r[2], r[3]);
        float a45 = __fadd_rn(r[4], r[5]), a67 = __fadd_rn(r[6], r[7]);
        cc[t] = __fadd_rn(__fadd_rn(a01, a23), __fadd_rn(a45, a67));
    }
    __syncthreads();
    for (int i = lo + t; i < lo + clen; i += KB) {
        float d0 = __fmul_rn(XT[i], cent[0]);
        float d1 = __fmul_rn(XT[i], cent[64]);
        float d2 = __fmul_rn(XT[i], cent[128]);
        float d3 = __fmul_rn(XT[i], cent[192]);
        for (int d = 1; d < 64; ++d) {
            float xv = XT[(size_t)d * N + i];
            d0 = __fadd_rn(d0, __fmul_rn(xv, cent[d]));
            d1 = __fadd_rn(d1, __fmul_rn(xv, cent[64 + d]));
            d2 = __fadd_rn(d2, __fmul_rn(xv, cent[128 + d]));
            d3 = __fadd_rn(d3, __fmul_rn(xv, cent[192 + d]));
        }
        float xi = xx[i];
        float q0 = __fsub_rn(__fadd_rn(xi, cc[0]), __fmul_rn(2.0f, d0));
        float q1 = __fsub_rn(__fadd_rn(xi, cc[1]), __fmul_rn(2.0f, d1));
        float q2 = __fsub_rn(__fadd_rn(xi, cc[2]), __fmul_rn(2.0f, d2));
        float q3 = __fsub_rn(__fadd_rn(xi, cc[3]), __fmul_rn(2.0f, d3));
        int kb = 0; float bv = q0;
        if (q1 < bv) { bv = q1; kb = 1; }
        if (q2 < bv) { bv = q2; kb = 2; }
        if (q3 < bv) { bv = q3; kb = 3; }
        assign[i] = kb;
    }
}

// ----------------------------------------------- conv4 f64 (R23-exact)
__global__ __launch_bounds__(256) void d_conv4(
    const float* __restrict__ edge_attr, const int* __restrict__ src,
    const int* __restrict__ dst, const int* __restrict__ assign,
    const int* __restrict__ deg, const float* __restrict__ w,
    const float* __restrict__ alpha, double* __restrict__ eacc, int E) {
    int e = blockIdx.x * 256 + threadIdx.x;
    if (e >= E) return;
    int s = src[e], d = dst[e];
    int ka = assign[s];
    if (assign[d] != ka) return;
    double a = (double)edge_attr[e];
    double f0[64], f1[64], f2[64], f3[64];
    for (int j = 0; j < 64; ++j) {
        double h0 = a * (double)w[j];
        double h1 = a * (double)w[64 + j];
        double h2 = a * (double)w[128 + j];
        double h3 = a * (double)w[192 + j];
        double l1 = h1 > 0.0 ? h1 : 0.1 * h1;
        double l2 = h2 > 0.0 ? h2 : 0.1 * h2;
        double l3 = h3 > 0.0 ? h3 : 0.1 * h3;
        f0[j] = h0;
        f1[j] = l1;
        f2[j] = l2 * l2;
        f3[j] = (l3 * l3) * l3;
    }
    double dg = (double)deg[s];
    const float* ab = alpha + (size_t)ka * 4 * 64 * 64;
    double* ep = eacc + (size_t)d * 64;
    for (int h = 0; h < 64; ++h) {
        const float* a0 = ab + (size_t)(0 * 64 + h) * 64;
        const float* a1 = ab + (size_t)(1 * 64 + h) * 64;
        const float* a2 = ab + (size_t)(2 * 64 + h) * 64;
        const float* a3 = ab + (size_t)(3 * 64 + h) * 64;
        double s0 = 0.0, s1 = 0.0, s2 = 0.0, s3 = 0.0;
        for (int j = 0; j < 64; ++j) {
            s0 = fma(f0[j], (double)a0[j], s0);
            s1 = fma(f1[j], (double)a1[j], s1);
            s2 = fma(f2[j], (double)a2[j], s2);
            s3 = fma(f3[j], (double)a3[j], s3);
        }
        double ew = ((s0 + s1) + s2) + s3;
        atomicAdd(&ep[h], ew / dg);
    }
}

// z[n] = sum_h eacc[n,h]*w3[h] + x[n]*w3[64]
__global__ void d_z(const double* __restrict__ eacc, const float* __restrict__ x,
                    const float* __restrict__ w3, double* __restrict__ z, int N) {
    int n = blockIdx.x * 256 + threadIdx.x;
    if (n >= N) return;
    const double* row = eacc + (size_t)n * 64;
    double v = 0.0;
    for (int h = 0; h < 64; ++h)
        v = fma(row[h], (double)w3[h], v);
    z[n] = v + (double)x[n] * (double)w3[64];
}

// qq[j] = (px*px)+(py*py), separate roundings (R23-exact)
__global__ void f_pp(const float* __restrict__ pl, float* __restrict__ pp, int N) {
    int i = blockIdx.x * 256 + threadIdx.x;
    if (i < N) {
        float px = pl[2 * i], py = pl[2 * i + 1];
        pp[i] = __fadd_rn(__fmul_rn(px, px), __fmul_rn(py, py));
    }
}

// -- KNN(4) f32 V6 (R23-exact): nonFMA dot + FMA combine, first-index ties
__global__ __launch_bounds__(256) void f_knn_out(
    const float* __restrict__ ph, const float* __restrict__ pl,
    const float* __restrict__ pp, const double* __restrict__ z,
    const float* __restrict__ c3b, float* __restrict__ out, int N, int NH) {
    int p = blockIdx.x * 256 + threadIdx.x;
    if (p >= NH) return;
    float hx = ph[2 * p], hy = ph[2 * p + 1];
    float hh = __fadd_rn(__fmul_rn(hx, hx), __fmul_rn(hy, hy));
    float b0 = FLT_MAX, b1 = FLT_MAX, b2 = FLT_MAX, b3 = FLT_MAX;
    int j0 = 0, j1 = 0, j2 = 0, j3 = 0;
    for (int j = 0; j < N; ++j) {
        float dot = __fadd_rn(__fmul_rn(hx, pl[2 * j]), __fmul_rn(hy, pl[2 * j + 1]));
        float t1  = __fadd_rn(hh, pp[j]);
        float dv  = __fmaf_rn(-2.0f, dot, t1);
        if (dv < b3) {
            if (dv < b2) {
                b3 = b2; j3 = j2;
                if (dv < b1) {
                    b2 = b1; j2 = j1;
                    if (dv < b0) { b1 = b0; j1 = j0; b0 = dv; j0 = j; }
                    else         { b1 = dv; j1 = j; }
                } else { b2 = dv; j2 = j; }
            } else { b3 = dv; j3 = j; }
        }
    }
    double zz = ((z[j0] + z[j1]) + z[j2]) + z[j3];
    out[p] = (float)(0.25 * zz + (double)c3b[0]);
}

// ------------------------------------------------------------------- launch
extern "C" void kernel_launch(void* const* d_in, const int* in_sizes, int n_in,
                              void* d_out, int out_size, void* d_ws, size_t ws_size,
                              hipStream_t stream) {
    float* out = (float*)d_out;

    static const int EXP[18] = {10000, 160000, 20000, 40000, 192, 64, 8192, 64,
                                4096, 64, 256, 65536, 256, 65536, 65, 1, 320000, 4};
    int bad = -1;
    if (n_in != 18) bad = 19;
    else for (int i = 0; i < 18; ++i) if (in_sizes[i] != EXP[i]) { bad = i; break; }
    if (bad >= 0) {
        d_sent<<<(out_size + 255) / 256, 256, 0, stream>>>(out, out_size,
                                                           ldexpf(1.0f, 30 + bad));
        return;
    }

    const float* x         = (const float*)d_in[0];
    const float* edge_attr = (const float*)d_in[1];
    const float* pos       = (const float*)d_in[2];
    const float* pos_high  = (const float*)d_in[3];
    const float* lin_w     = (const float*)d_in[4];
    const float* lin_b     = (const float*)d_in[5];
    const float* ec_w1     = (const float*)d_in[6];
    const float* ec_b1     = (const float*)d_in[7];
    const float* ec_w2     = (const float*)d_in[8];
    const float* ec_b2     = (const float*)d_in[9];
    const float* c4w       = (const float*)d_in[12];
    const float* c4a       = (const float*)d_in[13];
    const float* c3w       = (const float*)d_in[14];
    const float* c3b       = (const float*)d_in[15];
    const int*   eidx      = (const int*)d_in[16];
    const int*   kinit     = (const int*)d_in[17];
    int N  = in_sizes[0];
    int E  = in_sizes[1];
    int NH = in_sizes[3] / 2;
    const int* src  = eidx;
    const int* dstA = eidx + E;

    char* wsb = (char*)d_ws;
    size_t off = 0;
    auto alloc = [&](size_t bytes) -> char* {
        char* pp = wsb + off;
        off += (bytes + 255) & ~(size_t)255;
        return pp;
    };
    float*  XS   = (float*)alloc((size_t)N * 64 * 4);
    u32*    KEY  = (u32*)alloc((size_t)N * 64 * 4);     // -> xs2 f32 in place
    float*  XT   = (float*)alloc((size_t)N * 64 * 4);
    float*  XX   = (float*)alloc((size_t)N * 4);
    double* EACC = (double*)alloc((size_t)N * 64 * 8);
    int*    DEG  = (int*)alloc((size_t)N * 4);
    int*    ASG  = (int*)alloc((size_t)N * 4);
    unsigned char* ASG8 = (unsigned char*)alloc((size_t)N);
    double* Z    = (double*)alloc((size_t)N * 8);
    float*  PP   = (float*)alloc((size_t)N * 4);
    float*  PART = (float*)alloc(2 * KG * 256 * 4);
    float*  CNTS = (float*)alloc(2 * KG * 4 * 4);

    if (off > ws_size) {
        d_sent<<<(out_size + 255) / 256, 256, 0, stream>>>(out, out_size,
                                                           ldexpf(1.0f, 29));
        return;
    }

    hipMemsetAsync(DEG, 0, (size_t)N * 4, stream);
    hipMemsetAsync(EACC, 0, (size_t)N * 64 * 8, stream);

    f_xs<<<(N * 64 + 255) / 256, 256, 0, stream>>>(x, pos, lin_w, lin_b, XS, KEY, N);
    d_deg<<<(E + 255) / 256, 256, 0, stream>>>(src, DEG, E);
    f_edgeconv<<<(E + 255) / 256, 256, 0, stream>>>(XS, src, dstA, ec_w1, ec_b1,
                                                    ec_w2, ec_b2, KEY, E);
    f_xs2<<<(N * 64 + 255) / 256, 256, 0, stream>>>(KEY, N * 64);
    float* X2 = (float*)KEY;
    f_transpose<<<(N * 64 + 255) / 256, 256, 0, stream>>>(X2, XT, N);
    f_xx<<<(N + 255) / 256, 256, 0, stream>>>(X2, XX, N);
    {
        void* kargs[] = { (void*)&X2, (void*)&XT, (void*)&XX, (void*)&kinit,
                          (void*)&PART, (void*)&CNTS, (void*)&ASG8, (void*)&ASG,
                          (void*)&N };
        hipLaunchCooperativeKernel(reinterpret_cast<void*>(&f_kmeans_coop),
                                   dim3(KG), dim3(KB), kargs, 0, stream);
    }
    d_conv4<<<(E + 255) / 256, 256, 0, stream>>>(edge_attr, src, dstA, ASG, DEG,
                                                 c4w, c4a, EACC, E);
    d_z<<<(N + 255) / 256, 256, 0, stream>>>(EACC, x, c3w, Z, N);
    f_pp<<<(N + 255) / 256, 256, 0, stream>>>(pos, PP, N);
    f_knn_out<<<(NH + 255) / 256, 256, 0, stream>>>(pos_high, pos, PP, Z, c3b,
                                                    out, N, NH);
}